// Round 1
// baseline (16401.540 us; speedup 1.0000x reference)
//
#include <hip/hip_runtime.h>

#define NTRAJ   256
#define NTP     512
#define NSTEPS  511
#define LATENT  256
#define INPUT   128
#define DEC_OUT 128

#define OUT_VOL ((size_t)NTRAJ * LATENT)                              // 65536
#define OUT_DTS (OUT_VOL + (size_t)NTRAJ * NSTEPS * DEC_OUT)          // 16809984

__device__ __forceinline__ float wred(float v) {
    #pragma unroll
    for (int off = 32; off; off >>= 1) v += __shfl_down(v, off, 64);
    return v;
}
__device__ __forceinline__ float fast_sigmoid(float x) { return 1.0f / (1.0f + __expf(-x)); }
// tanh via exp2-based __expf; saturates cleanly (no NaN at +/-inf since 1-2/(e+1) form)
__device__ __forceinline__ float fast_tanh(float x) {
    float e = __expf(2.0f * x);
    return 1.0f - 2.0f / (e + 1.0f);
}

// out[j] = act( sum_k src[k] * W[k*256+j] + bias[j] ), j in [0,256)
// 4 waves split K; lane handles 4 consecutive cols via float4 (coalesced dwordx4:
// a wave's 64 lanes x 16B cover one full 1KB weight row).
// ACT: 0=none 1=relu 2=tanh 3=sigmoid.  dst==src is safe (write is after barrier).
template<int K, int ACT>
__device__ __forceinline__ void mm256(const float* __restrict__ W,
                                      const float* __restrict__ bias,
                                      const float* __restrict__ src,
                                      float* __restrict__ dst,
                                      float* __restrict__ part,
                                      int tid) {
    const int w = tid >> 6;
    const int c0 = (tid & 63) << 2;
    const int kbeg = w * (K >> 2);
    float ax = 0.f, ay = 0.f, az = 0.f, aw = 0.f;
    #pragma unroll 4
    for (int k = kbeg; k < kbeg + (K >> 2); k += 4) {
        float4 xk = *(const float4*)(src + k);
        float4 w0 = *(const float4*)(W + (k + 0) * 256 + c0);
        float4 w1 = *(const float4*)(W + (k + 1) * 256 + c0);
        float4 w2 = *(const float4*)(W + (k + 2) * 256 + c0);
        float4 w3 = *(const float4*)(W + (k + 3) * 256 + c0);
        ax += xk.x * w0.x + xk.y * w1.x + xk.z * w2.x + xk.w * w3.x;
        ay += xk.x * w0.y + xk.y * w1.y + xk.z * w2.y + xk.w * w3.y;
        az += xk.x * w0.z + xk.y * w1.z + xk.z * w2.z + xk.w * w3.z;
        aw += xk.x * w0.w + xk.y * w1.w + xk.z * w2.w + xk.w * w3.w;
    }
    *(float4*)(part + (w << 8) + c0) = make_float4(ax, ay, az, aw);
    __syncthreads();
    float v = part[tid] + part[256 + tid] + part[512 + tid] + part[768 + tid] + bias[tid];
    if (ACT == 1) v = fmaxf(v, 0.f);
    if (ACT == 2) v = fast_tanh(v);
    if (ACT == 3) v = fast_sigmoid(v);
    dst[tid] = v;
    __syncthreads();
}

// vol = src(256) @ dec_w(256x128) + dec_b -> global.  8 k-slices of 32, 32 lanes x 4 cols.
__device__ __forceinline__ void mm_dec(const float* __restrict__ W,
                                       const float* __restrict__ bias,
                                       const float* __restrict__ src,
                                       float* __restrict__ gout,
                                       float* __restrict__ part,
                                       int tid) {
    const int w = tid >> 5;
    const int c0 = (tid & 31) << 2;
    const int kbeg = w << 5;
    float ax = 0.f, ay = 0.f, az = 0.f, aw = 0.f;
    #pragma unroll 4
    for (int k = kbeg; k < kbeg + 32; k += 4) {
        float4 xk = *(const float4*)(src + k);
        float4 w0 = *(const float4*)(W + (k + 0) * 128 + c0);
        float4 w1 = *(const float4*)(W + (k + 1) * 128 + c0);
        float4 w2 = *(const float4*)(W + (k + 2) * 128 + c0);
        float4 w3 = *(const float4*)(W + (k + 3) * 128 + c0);
        ax += xk.x * w0.x + xk.y * w1.x + xk.z * w2.x + xk.w * w3.x;
        ay += xk.x * w0.y + xk.y * w1.y + xk.z * w2.y + xk.w * w3.y;
        az += xk.x * w0.z + xk.y * w1.z + xk.z * w2.z + xk.w * w3.z;
        aw += xk.x * w0.w + xk.y * w1.w + xk.z * w2.w + xk.w * w3.w;
    }
    *(float4*)(part + (w << 7) + c0) = make_float4(ax, ay, az, aw);
    __syncthreads();
    if (tid < 128) {
        float v = bias[tid];
        #pragma unroll
        for (int i = 0; i < 8; ++i) v += part[(i << 7) + tid];
        gout[tid] = v;
    }
    __syncthreads();
}

// One GRU step. s_in holds [y_param(256), xh(128)] on entry. r_ydec = y_param[tid].
__device__ __forceinline__ void gru_core(
    const float* ug_w1, const float* ug_b1, const float* ug_w2, const float* ug_b2,
    const float* ugt_w1, const float* ugt_b1, const float* ugt_w2, const float* ugt_b2,
    const float* rg_w1, const float* rg_b1, const float* rg_w2, const float* rg_b2,
    const float* ns_w1, const float* ns_b1, const float* ns_w2, const float* ns_b2,
    float* s_in, float* s_h, float* s_u, float* s_ut, float* s_r, float* s_part,
    float* s_y, float& r_yt, float r_ydec, bool mask, int tid)
{
    mm256<384, 2>(ug_w1, ug_b1, s_in, s_h, s_part, tid);
    mm256<256, 3>(ug_w2, ug_b2, s_h, s_u, s_part, tid);
    mm256<384, 2>(ugt_w1, ugt_b1, s_in, s_h, s_part, tid);
    mm256<256, 3>(ugt_w2, ugt_b2, s_h, s_ut, s_part, tid);
    mm256<384, 2>(rg_w1, rg_b1, s_in, s_h, s_part, tid);
    mm256<256, 3>(rg_w2, rg_b2, s_h, s_r, s_part, tid);
    // new_state input: [y_param * r, xh] (xh already staged in s_in[256..383])
    s_in[tid] = r_ydec * s_r[tid];
    __syncthreads();
    mm256<384, 2>(ns_w1, ns_b1, s_in, s_h, s_part, tid);
    mm256<256, 0>(ns_w2, ns_b2, s_h, s_h, s_part, tid);   // dst==src: safe
    float u = s_u[tid], ut = s_ut[tid], nsv = s_h[tid];
    float ny  = (1.f - u)  * nsv + u  * r_ydec;
    float nyt = (1.f - ut) * nsv + ut * r_yt;
    s_y[tid] = mask ? ny : r_ydec;       // mask=0: y <- y_param (= ydec_full)
    r_yt     = mask ? nyt : r_yt;
    __syncthreads();                      // s_y visible to next consumer
}

extern "C" __global__ void __launch_bounds__(256)
rnn_decay_kernel(const float* __restrict__ data, const float* __restrict__ ts,
                 const float* ug_w1, const float* ug_b1, const float* ug_w2, const float* ug_b2,
                 const float* ugt_w1, const float* ugt_b1, const float* ugt_w2, const float* ugt_b2,
                 const float* rg_w1, const float* rg_b1, const float* rg_w2, const float* rg_b2,
                 const float* ns_w1, const float* ns_b1, const float* ns_w2, const float* ns_b2,
                 const float* dk_w1, const float* dk_b1, const float* dk_w2, const float* dk_b2,
                 const float* dec_w, const float* dec_b,
                 float* __restrict__ out)
{
    __shared__ __align__(16) float s_y[256];
    __shared__ __align__(16) float s_in[384];
    __shared__ __align__(16) float s_part[1024];
    __shared__ __align__(16) float s_h[256];
    __shared__ __align__(16) float s_u[256];
    __shared__ __align__(16) float s_ut[256];
    __shared__ __align__(16) float s_r[256];
    __shared__ __align__(16) float s_vol[256];
    __shared__ float s_red[4];

    const int tid = threadIdx.x;
    const int w = tid >> 6;
    const int traj = blockIdx.x;
    const float* dbase = data + (size_t)traj * NTP * (2 * INPUT);
    const float* tbase = ts + (size_t)traj * NTP;
    float* vol_out = out + OUT_VOL + (size_t)traj * NSTEPS * DEC_OUT;
    float* dts_out = out + OUT_DTS + (size_t)traj * NSTEPS;

    // dts output (independent)
    for (int t = tid; t < NSTEPS; t += 256)
        dts_out[t] = tbase[t + 1] - tbase[t];

    float r_yt = 0.f;

    // ---- initial GRU: y = yt = 0, x = data[:,0,:] ----
    {
        float xv = dbase[tid];
        s_in[tid] = 0.f;                       // y_param = 0
        if (tid < 128) s_in[256 + tid] = xv;   // xh
        float mv = (tid >= 128) ? xv : 0.f;
        mv = wred(mv);
        if ((tid & 63) == 0) s_red[w] = mv;
        __syncthreads();
        bool mask = (s_red[0] + s_red[1] + s_red[2] + s_red[3]) > 0.f;
        gru_core(ug_w1, ug_b1, ug_w2, ug_b2, ugt_w1, ugt_b1, ugt_w2, ugt_b2,
                 rg_w1, rg_b1, rg_w2, rg_b2, ns_w1, ns_b1, ns_w2, ns_b2,
                 s_in, s_h, s_u, s_ut, s_r, s_part, s_y, r_yt, 0.f, mask, tid);
    }

    // ---- scan over 511 steps ----
    for (int t = 0; t < NSTEPS; ++t) {
        float xv = dbase[(size_t)(t + 1) * 256 + tid];
        float dt = tbase[t + 1] - tbase[t];

        float mv = (tid >= 128) ? xv : 0.f;
        mv = wred(mv);
        if ((tid & 63) == 0) s_red[w] = mv;
        __syncthreads();
        bool mask = (s_red[0] + s_red[1] + s_red[2] + s_red[3]) > 0.f;

        // decay MLP: relu(relu(y @ dk_w1 + b1) @ dk_w2 + b2)
        mm256<256, 1>(dk_w1, dk_b1, s_y, s_h, s_part, tid);
        float dv = s_h[tid] * dk_w2[tid];
        dv = wred(dv);
        if ((tid & 63) == 0) s_red[w] = dv;
        __syncthreads();
        float decay = fmaxf(s_red[0] + s_red[1] + s_red[2] + s_red[3] + dk_b2[0], 0.f);

        // ydec at lin = {0, 0.5, 1}; vol input = (ydec0 + ydec1)/2; gru input = ydec2
        float yj = s_y[tid];
        float diff = yj - r_yt;
        float ef = __expf(-decay * dt);
        float eh = __expf(-0.5f * decay * dt);
        float ydec = r_yt + diff * ef;
        s_in[tid] = ydec;
        if (tid < 128) s_in[256 + tid] = xv;
        s_vol[tid] = 0.5f * (yj + r_yt + diff * eh);
        __syncthreads();

        mm_dec(dec_w, dec_b, s_vol, vol_out + (size_t)t * DEC_OUT, s_part, tid);

        gru_core(ug_w1, ug_b1, ug_w2, ug_b2, ugt_w1, ugt_b1, ugt_w2, ugt_b2,
                 rg_w1, rg_b1, rg_w2, rg_b2, ns_w1, ns_b1, ns_w2, ns_b2,
                 s_in, s_h, s_u, s_ut, s_r, s_part, s_y, r_yt, ydec, mask, tid);
    }

    // prev_y = final y
    out[(size_t)traj * 256 + tid] = s_y[tid];
}

extern "C" void kernel_launch(void* const* d_in, const int* in_sizes, int n_in,
                              void* d_out, int out_size, void* d_ws, size_t ws_size,
                              hipStream_t stream) {
    const float* data   = (const float*)d_in[0];
    const float* ts     = (const float*)d_in[1];
    const float* ug_w1  = (const float*)d_in[2];
    const float* ug_b1  = (const float*)d_in[3];
    const float* ug_w2  = (const float*)d_in[4];
    const float* ug_b2  = (const float*)d_in[5];
    const float* ugt_w1 = (const float*)d_in[6];
    const float* ugt_b1 = (const float*)d_in[7];
    const float* ugt_w2 = (const float*)d_in[8];
    const float* ugt_b2 = (const float*)d_in[9];
    const float* rg_w1  = (const float*)d_in[10];
    const float* rg_b1  = (const float*)d_in[11];
    const float* rg_w2  = (const float*)d_in[12];
    const float* rg_b2  = (const float*)d_in[13];
    // d_in[14..17] = rgt_* : unused by the reference
    const float* ns_w1  = (const float*)d_in[18];
    const float* ns_b1  = (const float*)d_in[19];
    const float* ns_w2  = (const float*)d_in[20];
    const float* ns_b2  = (const float*)d_in[21];
    const float* dk_w1  = (const float*)d_in[22];
    const float* dk_b1  = (const float*)d_in[23];
    const float* dk_w2  = (const float*)d_in[24];
    const float* dk_b2  = (const float*)d_in[25];
    const float* dec_w  = (const float*)d_in[26];
    const float* dec_b  = (const float*)d_in[27];

    rnn_decay_kernel<<<NTRAJ, 256, 0, stream>>>(
        data, ts, ug_w1, ug_b1, ug_w2, ug_b2, ugt_w1, ugt_b1, ugt_w2, ugt_b2,
        rg_w1, rg_b1, rg_w2, rg_b2, ns_w1, ns_b1, ns_w2, ns_b2,
        dk_w1, dk_b1, dk_w2, dk_b2, dec_w, dec_b, (float*)d_out);
}

// Round 2
// 12963.144 us; speedup vs baseline: 1.2652x; 1.2652x over previous
//
#include <hip/hip_runtime.h>
#include <hip/hip_fp16.h>

#define NTRAJ   256
#define NTP     512
#define NSTEPS  511
#define LATENT  256
#define INPUT   128
#define DEC_OUT 128

#define OUT_VOL ((size_t)NTRAJ * LATENT)                              // 65536
#define OUT_DTS (OUT_VOL + (size_t)NTRAJ * NSTEPS * DEC_OUT)          // 16809984

// fp16 weight workspace layout (offsets in half elements)
#define W_UG1  0
#define W_UG2  98304
#define W_UGT1 163840
#define W_UGT2 262144
#define W_RG1  327680
#define W_RG2  425984
#define W_NS1  491520
#define W_NS2  589824
#define W_DK1  655360
#define W_DEC  720896
#define W_TOT  753664

__device__ __forceinline__ float wred(float v) {
    #pragma unroll
    for (int off = 32; off; off >>= 1) v += __shfl_down(v, off, 64);
    return v;
}
__device__ __forceinline__ float fast_sigmoid(float x) { return 1.0f / (1.0f + __expf(-x)); }
__device__ __forceinline__ float fast_tanh(float x) {
    float e = __expf(2.0f * x);
    return 1.0f - 2.0f / (e + 1.0f);
}

union HU { unsigned int u; __half2 h; };
__device__ __forceinline__ float2 h2f(unsigned int u) { HU t; t.u = u; return __half22float2(t.h); }

// Dual-trajectory GEMV: dst[p] = act(src[p] @ W + bias), W is fp16 [K][256].
// 8 waves split K (slice K/8); within a wave, lanes 0-31 handle k-row, lanes
// 32-63 handle k-row+1; each lane loads 8 fp16 cols as one 16B uint4 (full
// 1KB/wave-instr), FMAs into 8 accumulators for BOTH trajectories.
// ACT: 0=none 1=relu 2=tanh 3=sigmoid. dst may alias src (write after barrier).
template<int K, int ACT>
__device__ __forceinline__ void mm2_256(const __half* __restrict__ Wh,
                                        const float* __restrict__ bias,
                                        const float* __restrict__ src0,
                                        const float* __restrict__ src1,
                                        float* __restrict__ dst0,
                                        float* __restrict__ dst1,
                                        float* __restrict__ part, int tid) {
    const int w = tid >> 6;
    const int lane = tid & 63;
    const int hh = lane >> 5;           // which of 2 k-rows this lane covers
    const int c0 = (lane & 31) << 3;    // 8 cols per lane
    const int kbeg = w * (K >> 3) + hh;
    float a0[8] = {0,0,0,0,0,0,0,0};
    float a1[8] = {0,0,0,0,0,0,0,0};
    #pragma unroll 8
    for (int kk = 0; kk < (K >> 3); kk += 2) {
        const int k = kbeg + kk;
        const uint4 wv = *(const uint4*)(Wh + (size_t)k * 256 + c0);
        const float x0 = src0[k];
        const float x1 = src1[k];
        const float2 f0 = h2f(wv.x), f1 = h2f(wv.y), f2 = h2f(wv.z), f3 = h2f(wv.w);
        a0[0] = fmaf(x0, f0.x, a0[0]); a1[0] = fmaf(x1, f0.x, a1[0]);
        a0[1] = fmaf(x0, f0.y, a0[1]); a1[1] = fmaf(x1, f0.y, a1[1]);
        a0[2] = fmaf(x0, f1.x, a0[2]); a1[2] = fmaf(x1, f1.x, a1[2]);
        a0[3] = fmaf(x0, f1.y, a0[3]); a1[3] = fmaf(x1, f1.y, a1[3]);
        a0[4] = fmaf(x0, f2.x, a0[4]); a1[4] = fmaf(x1, f2.x, a1[4]);
        a0[5] = fmaf(x0, f2.y, a0[5]); a1[5] = fmaf(x1, f2.y, a1[5]);
        a0[6] = fmaf(x0, f3.x, a0[6]); a1[6] = fmaf(x1, f3.x, a1[6]);
        a0[7] = fmaf(x0, f3.y, a0[7]); a1[7] = fmaf(x1, f3.y, a1[7]);
    }
    // part layout: [p][w*2+hh][256]  -> p stride 4096, total 8192 floats
    float* p0 = part + ((w << 1) + hh) * 256 + c0;
    float* p1 = p0 + 4096;
    *(float4*)(p0)     = make_float4(a0[0], a0[1], a0[2], a0[3]);
    *(float4*)(p0 + 4) = make_float4(a0[4], a0[5], a0[6], a0[7]);
    *(float4*)(p1)     = make_float4(a1[0], a1[1], a1[2], a1[3]);
    *(float4*)(p1 + 4) = make_float4(a1[4], a1[5], a1[6], a1[7]);
    __syncthreads();
    const int p = tid >> 8, c = tid & 255;
    const float* pb = part + (p << 12) + c;
    float v = bias[c];
    #pragma unroll
    for (int i = 0; i < 16; ++i) v += pb[i << 8];
    if (ACT == 1) v = fmaxf(v, 0.f);
    if (ACT == 2) v = fast_tanh(v);
    if (ACT == 3) v = fast_sigmoid(v);
    (p ? dst1 : dst0)[c] = v;
    __syncthreads();
}

// vol[p] = src[p](256) @ dec_w(256x128,fp16) + dec_b -> global
__device__ __forceinline__ void mm2_dec(const __half* __restrict__ Wh,
                                        const float* __restrict__ bias,
                                        const float* __restrict__ src0,
                                        const float* __restrict__ src1,
                                        float* __restrict__ g0, float* __restrict__ g1,
                                        float* __restrict__ part, int tid) {
    const int w = tid >> 6;
    const int lane = tid & 63;
    const int sub = lane >> 4;          // 4 k-rows per wave-iter
    const int c0 = (lane & 15) << 3;    // 8 of 128 cols
    const int kbeg = (w << 5) + sub;
    float a0[8] = {0,0,0,0,0,0,0,0};
    float a1[8] = {0,0,0,0,0,0,0,0};
    #pragma unroll
    for (int kk = 0; kk < 32; kk += 4) {
        const int k = kbeg + kk;
        const uint4 wv = *(const uint4*)(Wh + (size_t)k * 128 + c0);
        const float x0 = src0[k];
        const float x1 = src1[k];
        const float2 f0 = h2f(wv.x), f1 = h2f(wv.y), f2 = h2f(wv.z), f3 = h2f(wv.w);
        a0[0] = fmaf(x0, f0.x, a0[0]); a1[0] = fmaf(x1, f0.x, a1[0]);
        a0[1] = fmaf(x0, f0.y, a0[1]); a1[1] = fmaf(x1, f0.y, a1[1]);
        a0[2] = fmaf(x0, f1.x, a0[2]); a1[2] = fmaf(x1, f1.x, a1[2]);
        a0[3] = fmaf(x0, f1.y, a0[3]); a1[3] = fmaf(x1, f1.y, a1[3]);
        a0[4] = fmaf(x0, f2.x, a0[4]); a1[4] = fmaf(x1, f2.x, a1[4]);
        a0[5] = fmaf(x0, f2.y, a0[5]); a1[5] = fmaf(x1, f2.y, a1[5]);
        a0[6] = fmaf(x0, f3.x, a0[6]); a1[6] = fmaf(x1, f3.x, a1[6]);
        a0[7] = fmaf(x0, f3.y, a0[7]); a1[7] = fmaf(x1, f3.y, a1[7]);
    }
    // part layout: [p][w*4+sub][128] -> p stride 4096
    float* p0 = part + ((w << 2) + sub) * 128 + c0;
    float* p1 = p0 + 4096;
    *(float4*)(p0)     = make_float4(a0[0], a0[1], a0[2], a0[3]);
    *(float4*)(p0 + 4) = make_float4(a0[4], a0[5], a0[6], a0[7]);
    *(float4*)(p1)     = make_float4(a1[0], a1[1], a1[2], a1[3]);
    *(float4*)(p1 + 4) = make_float4(a1[4], a1[5], a1[6], a1[7]);
    __syncthreads();
    if (tid < 256) {
        const int p = tid >> 7, c = tid & 127;
        const float* pb = part + (p << 12) + c;
        float v = bias[c];
        #pragma unroll
        for (int i = 0; i < 32; ++i) v += pb[i << 7];
        (p ? g1 : g0)[c] = v;
    }
    __syncthreads();
}

// One GRU step for both trajectories. s_in holds [y_param(256), xh(128)] per p
// (stride 384). r_ydec/r_yt/mask are this thread's (p = tid>>8, c = tid&255).
__device__ __forceinline__ void gru2(
    const __half* ug1, const float* ug_b1, const __half* ug2, const float* ug_b2,
    const __half* ugt1, const float* ugt_b1, const __half* ugt2, const float* ugt_b2,
    const __half* rg1, const float* rg_b1, const __half* rg2, const float* rg_b2,
    const __half* ns1, const float* ns_b1, const __half* ns2, const float* ns_b2,
    float* s_in, float* s_h, float* s_u, float* s_ut, float* s_r, float* s_part,
    float* s_y, float& r_yt, float r_ydec, bool mask, int tid)
{
    mm2_256<384, 2>(ug1, ug_b1, s_in, s_in + 384, s_h, s_h + 256, s_part, tid);
    mm2_256<256, 3>(ug2, ug_b2, s_h, s_h + 256, s_u, s_u + 256, s_part, tid);
    mm2_256<384, 2>(ugt1, ugt_b1, s_in, s_in + 384, s_h, s_h + 256, s_part, tid);
    mm2_256<256, 3>(ugt2, ugt_b2, s_h, s_h + 256, s_ut, s_ut + 256, s_part, tid);
    mm2_256<384, 2>(rg1, rg_b1, s_in, s_in + 384, s_h, s_h + 256, s_part, tid);
    mm2_256<256, 3>(rg2, rg_b2, s_h, s_h + 256, s_r, s_r + 256, s_part, tid);
    const int p = tid >> 8, c = tid & 255;
    s_in[p * 384 + c] = r_ydec * s_r[(p << 8) + c];
    __syncthreads();
    mm2_256<384, 2>(ns1, ns_b1, s_in, s_in + 384, s_h, s_h + 256, s_part, tid);
    mm2_256<256, 0>(ns2, ns_b2, s_h, s_h + 256, s_h, s_h + 256, s_part, tid);
    const float u = s_u[(p << 8) + c], ut = s_ut[(p << 8) + c], nsv = s_h[(p << 8) + c];
    const float ny  = (1.f - u)  * nsv + u  * r_ydec;
    const float nyt = (1.f - ut) * nsv + ut * r_yt;
    s_y[(p << 8) + c] = mask ? ny : r_ydec;
    r_yt              = mask ? nyt : r_yt;
    __syncthreads();
}

extern "C" __global__ void __launch_bounds__(256)
convert_w(const float* __restrict__ ug_w1, const float* __restrict__ ug_w2,
          const float* __restrict__ ugt_w1, const float* __restrict__ ugt_w2,
          const float* __restrict__ rg_w1, const float* __restrict__ rg_w2,
          const float* __restrict__ ns_w1, const float* __restrict__ ns_w2,
          const float* __restrict__ dk_w1, const float* __restrict__ dec_w,
          __half* __restrict__ ws)
{
    const int i = blockIdx.x * 256 + threadIdx.x;
    const float* s; int o;
    if      (i < W_UG2)  { s = ug_w1;  o = i; }
    else if (i < W_UGT1) { s = ug_w2;  o = i - W_UG2; }
    else if (i < W_UGT2) { s = ugt_w1; o = i - W_UGT1; }
    else if (i < W_RG1)  { s = ugt_w2; o = i - W_UGT2; }
    else if (i < W_RG2)  { s = rg_w1;  o = i - W_RG1; }
    else if (i < W_NS1)  { s = rg_w2;  o = i - W_RG2; }
    else if (i < W_NS2)  { s = ns_w1;  o = i - W_NS1; }
    else if (i < W_DK1)  { s = ns_w2;  o = i - W_NS2; }
    else if (i < W_DEC)  { s = dk_w1;  o = i - W_DK1; }
    else                 { s = dec_w;  o = i - W_DEC; }
    ws[i] = __float2half(s[o]);
}

extern "C" __global__ void __launch_bounds__(512)
rnn_decay_kernel2(const float* __restrict__ data, const float* __restrict__ ts,
                  const float* __restrict__ ug_b1, const float* __restrict__ ug_b2,
                  const float* __restrict__ ugt_b1, const float* __restrict__ ugt_b2,
                  const float* __restrict__ rg_b1, const float* __restrict__ rg_b2,
                  const float* __restrict__ ns_b1, const float* __restrict__ ns_b2,
                  const float* __restrict__ dk_b1, const float* __restrict__ dk_w2,
                  const float* __restrict__ dk_b2, const float* __restrict__ dec_b,
                  const __half* __restrict__ wsh, float* __restrict__ out)
{
    __shared__ __align__(16) float s_part[8192];
    __shared__ __align__(16) float s_in[768];
    __shared__ __align__(16) float s_h[512];
    __shared__ __align__(16) float s_u[512];
    __shared__ __align__(16) float s_ut[512];
    __shared__ __align__(16) float s_r[512];
    __shared__ __align__(16) float s_y[512];
    __shared__ __align__(16) float s_vol[512];
    __shared__ float s_red[8];

    const int tid = threadIdx.x;
    const int w = tid >> 6;
    const int p = tid >> 8;
    const int c = tid & 255;
    const int traj = (blockIdx.x << 1) + p;

    const __half* UG1  = wsh + W_UG1;  const __half* UG2  = wsh + W_UG2;
    const __half* UGT1 = wsh + W_UGT1; const __half* UGT2 = wsh + W_UGT2;
    const __half* RG1  = wsh + W_RG1;  const __half* RG2  = wsh + W_RG2;
    const __half* NS1  = wsh + W_NS1;  const __half* NS2  = wsh + W_NS2;
    const __half* DK1  = wsh + W_DK1;  const __half* DECW = wsh + W_DEC;

    const float* dbase = data + (size_t)traj * NTP * (2 * INPUT);
    const float* tbase = ts + (size_t)traj * NTP;
    float* vol0 = out + OUT_VOL + ((size_t)(blockIdx.x << 1) + 0) * NSTEPS * DEC_OUT;
    float* vol1 = out + OUT_VOL + ((size_t)(blockIdx.x << 1) + 1) * NSTEPS * DEC_OUT;
    float* dts_out = out + OUT_DTS + (size_t)traj * NSTEPS;

    for (int t = c; t < NSTEPS; t += 256)
        dts_out[t] = tbase[t + 1] - tbase[t];

    float r_yt = 0.f;

    // ---- initial GRU: y = yt = 0, x = data[:,0,:] ----
    {
        const float xv = dbase[c];
        s_in[p * 384 + c] = 0.f;
        if (c < 128) s_in[p * 384 + 256 + c] = xv;
        float mv = (c >= 128) ? xv : 0.f;
        mv = wred(mv);
        if ((tid & 63) == 0) s_red[w] = mv;
        __syncthreads();
        const bool mask = (s_red[p << 2] + s_red[(p << 2) + 1] +
                           s_red[(p << 2) + 2] + s_red[(p << 2) + 3]) > 0.f;
        gru2(UG1, ug_b1, UG2, ug_b2, UGT1, ugt_b1, UGT2, ugt_b2,
             RG1, rg_b1, RG2, rg_b2, NS1, ns_b1, NS2, ns_b2,
             s_in, s_h, s_u, s_ut, s_r, s_part, s_y, r_yt, 0.f, mask, tid);
    }

    // ---- 511 sequential steps ----
    for (int t = 0; t < NSTEPS; ++t) {
        const float xv = dbase[(size_t)(t + 1) * 256 + c];
        const float dt = tbase[t + 1] - tbase[t];

        float mv = (c >= 128) ? xv : 0.f;
        mv = wred(mv);
        if ((tid & 63) == 0) s_red[w] = mv;
        __syncthreads();
        const bool mask = (s_red[p << 2] + s_red[(p << 2) + 1] +
                           s_red[(p << 2) + 2] + s_red[(p << 2) + 3]) > 0.f;

        // decay = relu(relu(y@dk_w1+b1)@dk_w2+b2)
        mm2_256<256, 1>(DK1, dk_b1, s_y, s_y + 256, s_h, s_h + 256, s_part, tid);
        float dv = s_h[(p << 8) + c] * dk_w2[c];
        dv = wred(dv);
        __syncthreads();                 // all reads of s_red (mask) done
        if ((tid & 63) == 0) s_red[w] = dv;
        __syncthreads();
        const float decay = fmaxf(s_red[p << 2] + s_red[(p << 2) + 1] +
                                  s_red[(p << 2) + 2] + s_red[(p << 2) + 3] + dk_b2[0], 0.f);

        const float yj = s_y[(p << 8) + c];
        const float diff = yj - r_yt;
        const float ef = __expf(-decay * dt);
        const float eh = __expf(-0.5f * decay * dt);
        const float ydec = r_yt + diff * ef;
        s_in[p * 384 + c] = ydec;
        if (c < 128) s_in[p * 384 + 256 + c] = xv;
        s_vol[(p << 8) + c] = 0.5f * (yj + r_yt + diff * eh);
        __syncthreads();

        mm2_dec(DECW, dec_b, s_vol, s_vol + 256,
                vol0 + (size_t)t * DEC_OUT, vol1 + (size_t)t * DEC_OUT, s_part, tid);

        gru2(UG1, ug_b1, UG2, ug_b2, UGT1, ugt_b1, UGT2, ugt_b2,
             RG1, rg_b1, RG2, rg_b2, NS1, ns_b1, NS2, ns_b2,
             s_in, s_h, s_u, s_ut, s_r, s_part, s_y, r_yt, ydec, mask, tid);
    }

    out[(size_t)traj * 256 + c] = s_y[(p << 8) + c];
}

extern "C" void kernel_launch(void* const* d_in, const int* in_sizes, int n_in,
                              void* d_out, int out_size, void* d_ws, size_t ws_size,
                              hipStream_t stream) {
    const float* data   = (const float*)d_in[0];
    const float* ts     = (const float*)d_in[1];
    const float* ug_w1  = (const float*)d_in[2];
    const float* ug_b1  = (const float*)d_in[3];
    const float* ug_w2  = (const float*)d_in[4];
    const float* ug_b2  = (const float*)d_in[5];
    const float* ugt_w1 = (const float*)d_in[6];
    const float* ugt_b1 = (const float*)d_in[7];
    const float* ugt_w2 = (const float*)d_in[8];
    const float* ugt_b2 = (const float*)d_in[9];
    const float* rg_w1  = (const float*)d_in[10];
    const float* rg_b1  = (const float*)d_in[11];
    const float* rg_w2  = (const float*)d_in[12];
    const float* rg_b2  = (const float*)d_in[13];
    // d_in[14..17] = rgt_* : unused by the reference
    const float* ns_w1  = (const float*)d_in[18];
    const float* ns_b1  = (const float*)d_in[19];
    const float* ns_w2  = (const float*)d_in[20];
    const float* ns_b2  = (const float*)d_in[21];
    const float* dk_w1  = (const float*)d_in[22];
    const float* dk_b1  = (const float*)d_in[23];
    const float* dk_w2  = (const float*)d_in[24];
    const float* dk_b2  = (const float*)d_in[25];
    const float* dec_w  = (const float*)d_in[26];
    const float* dec_b  = (const float*)d_in[27];

    __half* wsh = (__half*)d_ws;

    convert_w<<<W_TOT / 256, 256, 0, stream>>>(ug_w1, ug_w2, ugt_w1, ugt_w2,
                                               rg_w1, rg_w2, ns_w1, ns_w2,
                                               dk_w1, dec_w, wsh);

    rnn_decay_kernel2<<<NTRAJ / 2, 512, 0, stream>>>(
        data, ts, ug_b1, ug_b2, ugt_b1, ugt_b2, rg_b1, rg_b2, ns_b1, ns_b2,
        dk_b1, dk_w2, dk_b2, dec_b, wsh, (float*)d_out);
}

// Round 3
// 7574.616 us; speedup vs baseline: 2.1653x; 1.7114x over previous
//
#include <hip/hip_runtime.h>
#include <hip/hip_fp16.h>

#define NTRAJ   256
#define NTP     512
#define NSTEPS  511
#define LATENT  256
#define INPUT   128
#define DEC_OUT 128

#define OUT_VOL ((size_t)NTRAJ * LATENT)                              // 65536
#define OUT_DTS (OUT_VOL + (size_t)NTRAJ * NSTEPS * DEC_OUT)          // 16809984

// Pair-interleaved fp16 weight workspace (offsets in uint32 = half2 units).
// Layout per matrix [K][C]: ws[kp*C + c] = half2(W[2kp][c], W[2kp+1][c]).
#define WU_UG1  0
#define WU_UG2  49152
#define WU_UGT1 81920
#define WU_UGT2 131072
#define WU_RG1  163840
#define WU_RG2  212992
#define WU_NS1  245760
#define WU_NS2  294912
#define WU_DK1  327680
#define WU_DEC  360448
#define WU_TOT  376832

typedef _Float16 h2_t __attribute__((ext_vector_type(2)));
union U32H2 { unsigned int u; h2_t h; };

__device__ __forceinline__ float dot2f(unsigned int wu, unsigned int xu, float acc) {
#if defined(__has_builtin) && __has_builtin(__builtin_amdgcn_fdot2)
    U32H2 a, b; a.u = wu; b.u = xu;
    return __builtin_amdgcn_fdot2(a.h, b.h, acc, false);
#else
    U32H2 a, b; a.u = wu; b.u = xu;
    return acc + (float)a.h.x * (float)b.h.x + (float)a.h.y * (float)b.h.y;
#endif
}

__device__ __forceinline__ float wred(float v) {
    #pragma unroll
    for (int off = 32; off; off >>= 1) v += __shfl_down(v, off, 64);
    return v;
}
__device__ __forceinline__ float fast_sigmoid(float x) { return 1.0f / (1.0f + __expf(-x)); }
__device__ __forceinline__ float fast_tanh(float x) {
    float e = __expf(2.0f * x);
    return 1.0f - 2.0f / (e + 1.0f);
}
// Pack (v_even, v_odd) from adjacent lanes into one half2; only even lanes
// hold the correct result and write. Must be called by full waves.
__device__ __forceinline__ unsigned int packpair(float v) {
    float vn = __shfl_xor(v, 1, 64);
    U32H2 r; r.h.x = (_Float16)v; r.h.y = (_Float16)vn;
    return r.u;
}

// ---- weight prep: fp32 -> k-pair-interleaved half2 ----
extern "C" __global__ void __launch_bounds__(256)
convert_w(const float* __restrict__ ug_w1, const float* __restrict__ ug_w2,
          const float* __restrict__ ugt_w1, const float* __restrict__ ugt_w2,
          const float* __restrict__ rg_w1, const float* __restrict__ rg_w2,
          const float* __restrict__ ns_w1, const float* __restrict__ ns_w2,
          const float* __restrict__ dk_w1, const float* __restrict__ dec_w,
          unsigned int* __restrict__ ws)
{
    const int i = blockIdx.x * 256 + threadIdx.x;
    const float* s; int o; int cbits;
    if      (i < WU_UG2)  { s = ug_w1;  o = i;           cbits = 8; }
    else if (i < WU_UGT1) { s = ug_w2;  o = i - WU_UG2;  cbits = 8; }
    else if (i < WU_UGT2) { s = ugt_w1; o = i - WU_UGT1; cbits = 8; }
    else if (i < WU_RG1)  { s = ugt_w2; o = i - WU_UGT2; cbits = 8; }
    else if (i < WU_RG2)  { s = rg_w1;  o = i - WU_RG1;  cbits = 8; }
    else if (i < WU_NS1)  { s = rg_w2;  o = i - WU_RG2;  cbits = 8; }
    else if (i < WU_NS2)  { s = ns_w1;  o = i - WU_NS1;  cbits = 8; }
    else if (i < WU_DK1)  { s = ns_w2;  o = i - WU_NS2;  cbits = 8; }
    else if (i < WU_DEC)  { s = dk_w1;  o = i - WU_DK1;  cbits = 8; }
    else                  { s = dec_w;  o = i - WU_DEC;  cbits = 7; }
    const int C  = 1 << cbits;
    const int kp = o >> cbits;
    const int c  = o & (C - 1);
    const float v0 = s[(2 * kp) * C + c];
    const float v1 = s[(2 * kp + 1) * C + c];
    const unsigned int h0 = __half_as_ushort(__float2half(v0));
    const unsigned int h1 = __half_as_ushort(__float2half(v1));
    ws[i] = h0 | (h1 << 16);
}

extern "C" __global__ void __launch_bounds__(512, 2)
rnn_decay_kernel3(const float* __restrict__ data, const float* __restrict__ ts,
                  const float* __restrict__ ug_b1, const float* __restrict__ ug_b2,
                  const float* __restrict__ ugt_b1, const float* __restrict__ ugt_b2,
                  const float* __restrict__ rg_b1, const float* __restrict__ rg_b2,
                  const float* __restrict__ ns_b1, const float* __restrict__ ns_b2,
                  const float* __restrict__ dk_b1, const float* __restrict__ dk_w2,
                  const float* __restrict__ dk_b2, const float* __restrict__ dec_b,
                  const unsigned int* __restrict__ wsu, float* __restrict__ out)
{
    __shared__ __align__(16) float s_part[8192];        // GEMV partials (reused)
    __shared__ unsigned int s_in_h[192];                // [ydec(128)|xh(64)] half2
    __shared__ unsigned int s_ns_h[192];                // [y*r (128)|xh(64)] half2
    __shared__ unsigned int s_y_h[128];                 // y half2 (dk1 src)
    __shared__ unsigned int s_a_h[128];                 // gate-h / ns-h half2
    __shared__ unsigned int s_b_h[128];
    __shared__ unsigned int s_c_h[128];
    __shared__ unsigned int s_v_h[128];                 // vol half2
    __shared__ float s_ut[256];
    __shared__ float s_red[8];                          // [0..3] mask, [4..7] dk

    const int tid  = threadIdx.x;
    const int w    = tid >> 6;
    const int lane = tid & 63;
    const int c    = tid & 255;
    const int cl4  = lane << 2;                          // 4 uint cols per lane
    const int traj = blockIdx.x;

    const unsigned int* UG1  = wsu + WU_UG1;  const unsigned int* UG2  = wsu + WU_UG2;
    const unsigned int* UGT1 = wsu + WU_UGT1; const unsigned int* UGT2 = wsu + WU_UGT2;
    const unsigned int* RG1  = wsu + WU_RG1;  const unsigned int* RG2  = wsu + WU_RG2;
    const unsigned int* NS1  = wsu + WU_NS1;  const unsigned int* NS2  = wsu + WU_NS2;
    const unsigned int* DK1  = wsu + WU_DK1;  const unsigned int* DECW = wsu + WU_DEC;

    const float* dbase = data + (size_t)traj * NTP * (2 * INPUT);
    const float* tbase = ts + (size_t)traj * NTP;
    float* vol_out = out + OUT_VOL + (size_t)traj * NSTEPS * DEC_OUT;
    float* dts_out = out + OUT_DTS + (size_t)traj * NSTEPS;

    if (tid < 256)
        for (int t = c; t < NSTEPS; t += 256)
            dts_out[t] = tbase[t + 1] - tbase[t];

    float r_y = 0.f, r_yt = 0.f;

    for (int t = -1; t < NSTEPS; ++t) {
        const bool first = (t < 0);

        // ---- stage x, mask partials, xh pack ----
        if (tid < 256) {
            const float xv = first ? dbase[c] : dbase[(size_t)(t + 1) * 256 + c];
            float mv = (c >= 128) ? xv : 0.f;
            mv = wred(mv);
            if (lane == 0) s_red[w] = mv;               // w in 0..3 here
            if (c < 128) {
                const unsigned int px = packpair(xv);
                if (!(lane & 1)) { s_in_h[128 + (c >> 1)] = px; s_ns_h[128 + (c >> 1)] = px; }
            }
            if (first && !(lane & 1)) s_in_h[c >> 1] = 0u;   // ydec = 0
        }

        float r_ydec = 0.f, r_u = 0.f, r_r = 0.f;
        bool maskv;

        if (!first) {
            // ---- dk1: y @ dk_w1, K=256 (src s_y_h from prev iter) ----
            float4 aD = make_float4(0, 0, 0, 0);
            const int kp0 = w << 4;
            #pragma unroll 4
            for (int i = 0; i < 16; ++i) {
                const unsigned int x = s_y_h[kp0 + i];
                const uint4 wv = *(const uint4*)(DK1 + (size_t)(kp0 + i) * 256 + cl4);
                aD.x = dot2f(wv.x, x, aD.x); aD.y = dot2f(wv.y, x, aD.y);
                aD.z = dot2f(wv.z, x, aD.z); aD.w = dot2f(wv.w, x, aD.w);
            }
            *(float4*)(s_part + (w << 8) + cl4) = aD;
            __syncthreads();                                           // B1
            if (tid < 256) {
                float v = dk_b1[c];
                #pragma unroll
                for (int i = 0; i < 8; ++i) v += s_part[(i << 8) + c];
                v = fmaxf(v, 0.f);
                float pv = wred(v * dk_w2[c]);
                if (lane == 0) s_red[4 + w] = pv;
            }
            __syncthreads();                                           // B2
            const float decay = fmaxf(s_red[4] + s_red[5] + s_red[6] + s_red[7] + dk_b2[0], 0.f);
            maskv = (s_red[0] + s_red[1] + s_red[2] + s_red[3]) > 0.f;
            if (tid < 256) {
                const float dt = tbase[t + 1] - tbase[t];
                const float diff = r_y - r_yt;
                const float ef = __expf(-decay * dt);
                const float eh = __expf(-0.5f * decay * dt);
                r_ydec = r_yt + diff * ef;
                const float vol = 0.5f * (r_y + r_yt + diff * eh);
                const unsigned int pd = packpair(r_ydec);
                const unsigned int pvv = packpair(vol);
                if (!(lane & 1)) { s_in_h[c >> 1] = pd; s_v_h[c >> 1] = pvv; }
            }
            __syncthreads();                                           // B3
        } else {
            __syncthreads();                                           // B3
            maskv = (s_red[0] + s_red[1] + s_red[2] + s_red[3]) > 0.f;
        }

        // ---- group1: ug1/ugt1/rg1 (K=384, src s_in_h) + dec (K=256, src s_v_h) ----
        if (!first) {
            float4 aE = make_float4(0, 0, 0, 0);
            const int hh = lane >> 5, cl = (lane & 31) << 2;
            const int kpb = (w << 4) + hh;
            #pragma unroll 4
            for (int i = 0; i < 8; ++i) {
                const int kp = kpb + (i << 1);
                const uint4 wv = *(const uint4*)(DECW + (size_t)kp * 128 + cl);
                const unsigned int x = s_v_h[kp];
                aE.x = dot2f(wv.x, x, aE.x); aE.y = dot2f(wv.y, x, aE.y);
                aE.z = dot2f(wv.z, x, aE.z); aE.w = dot2f(wv.w, x, aE.w);
            }
            *(float4*)(s_part + 6144 + ((w << 1) + hh) * 128 + cl) = aE;
        }
        {
            float4 aA = make_float4(0, 0, 0, 0), aB = aA, aC = aA;
            const int kp0 = w * 24;
            #pragma unroll 4
            for (int i = 0; i < 24; ++i) {
                const int kp = kp0 + i;
                const unsigned int x = s_in_h[kp];
                const uint4 wa = *(const uint4*)(UG1  + (size_t)kp * 256 + cl4);
                const uint4 wb = *(const uint4*)(UGT1 + (size_t)kp * 256 + cl4);
                const uint4 wc = *(const uint4*)(RG1  + (size_t)kp * 256 + cl4);
                aA.x = dot2f(wa.x, x, aA.x); aA.y = dot2f(wa.y, x, aA.y);
                aA.z = dot2f(wa.z, x, aA.z); aA.w = dot2f(wa.w, x, aA.w);
                aB.x = dot2f(wb.x, x, aB.x); aB.y = dot2f(wb.y, x, aB.y);
                aB.z = dot2f(wb.z, x, aB.z); aB.w = dot2f(wb.w, x, aB.w);
                aC.x = dot2f(wc.x, x, aC.x); aC.y = dot2f(wc.y, x, aC.y);
                aC.z = dot2f(wc.z, x, aC.z); aC.w = dot2f(wc.w, x, aC.w);
            }
            *(float4*)(s_part + (w << 8) + cl4)          = aA;
            *(float4*)(s_part + 2048 + (w << 8) + cl4)   = aB;
            *(float4*)(s_part + 4096 + (w << 8) + cl4)   = aC;
        }
        __syncthreads();                                               // B4
        {   // reduce + tanh + pack to half2 srcs
            const int s = tid >> 8;
            float v = (s ? ugt_b1 : ug_b1)[c];
            const float* pb = s_part + (s ? 2048 : 0) + c;
            #pragma unroll
            for (int i = 0; i < 8; ++i) v += pb[i << 8];
            v = fast_tanh(v);
            const unsigned int pk = packpair(v);
            if (!(lane & 1)) (s ? s_b_h : s_a_h)[c >> 1] = pk;
            if (tid < 256) {
                float v2 = rg_b1[c];
                const float* pb2 = s_part + 4096 + c;
                #pragma unroll
                for (int i = 0; i < 8; ++i) v2 += pb2[i << 8];
                v2 = fast_tanh(v2);
                const unsigned int pk2 = packpair(v2);
                if (!(lane & 1)) s_c_h[c >> 1] = pk2;
            }
            if (!first && tid < 128) {
                float vd = dec_b[tid];
                const float* pbd = s_part + 6144 + tid;
                #pragma unroll
                for (int i = 0; i < 16; ++i) vd += pbd[i << 7];
                vol_out[(size_t)t * DEC_OUT + tid] = vd;
            }
        }
        __syncthreads();                                               // B5

        // ---- group2: ug2/ugt2/rg2 (K=256; srcs s_a_h, s_b_h, s_c_h) ----
        {
            float4 aA = make_float4(0, 0, 0, 0), aB = aA, aC = aA;
            const int kp0 = w << 4;
            #pragma unroll 4
            for (int i = 0; i < 16; ++i) {
                const int kp = kp0 + i;
                const unsigned int xa = s_a_h[kp];
                const unsigned int xb = s_b_h[kp];
                const unsigned int xc = s_c_h[kp];
                const uint4 wa = *(const uint4*)(UG2  + (size_t)kp * 256 + cl4);
                const uint4 wb = *(const uint4*)(UGT2 + (size_t)kp * 256 + cl4);
                const uint4 wc = *(const uint4*)(RG2  + (size_t)kp * 256 + cl4);
                aA.x = dot2f(wa.x, xa, aA.x); aA.y = dot2f(wa.y, xa, aA.y);
                aA.z = dot2f(wa.z, xa, aA.z); aA.w = dot2f(wa.w, xa, aA.w);
                aB.x = dot2f(wb.x, xb, aB.x); aB.y = dot2f(wb.y, xb, aB.y);
                aB.z = dot2f(wb.z, xb, aB.z); aB.w = dot2f(wb.w, xb, aB.w);
                aC.x = dot2f(wc.x, xc, aC.x); aC.y = dot2f(wc.y, xc, aC.y);
                aC.z = dot2f(wc.z, xc, aC.z); aC.w = dot2f(wc.w, xc, aC.w);
            }
            *(float4*)(s_part + (w << 8) + cl4)          = aA;
            *(float4*)(s_part + 2048 + (w << 8) + cl4)   = aB;
            *(float4*)(s_part + 4096 + (w << 8) + cl4)   = aC;
        }
        __syncthreads();                                               // B6
        {
            const int s = tid >> 8;
            float v = (s ? ugt_b2 : ug_b2)[c];
            const float* pb = s_part + (s ? 2048 : 0) + c;
            #pragma unroll
            for (int i = 0; i < 8; ++i) v += pb[i << 8];
            v = fast_sigmoid(v);
            if (s) s_ut[c] = v; else r_u = v;
            if (tid < 256) {
                float v2 = rg_b2[c];
                const float* pb2 = s_part + 4096 + c;
                #pragma unroll
                for (int i = 0; i < 8; ++i) v2 += pb2[i << 8];
                r_r = fast_sigmoid(v2);
                const unsigned int pk = packpair(r_ydec * r_r);
                if (!(lane & 1)) s_ns_h[c >> 1] = pk;
            }
        }
        __syncthreads();                                               // B7

        // ---- ns1 (K=384, src s_ns_h) ----
        {
            float4 aA = make_float4(0, 0, 0, 0);
            const int kp0 = w * 24;
            #pragma unroll 4
            for (int i = 0; i < 24; ++i) {
                const int kp = kp0 + i;
                const unsigned int x = s_ns_h[kp];
                const uint4 wa = *(const uint4*)(NS1 + (size_t)kp * 256 + cl4);
                aA.x = dot2f(wa.x, x, aA.x); aA.y = dot2f(wa.y, x, aA.y);
                aA.z = dot2f(wa.z, x, aA.z); aA.w = dot2f(wa.w, x, aA.w);
            }
            *(float4*)(s_part + (w << 8) + cl4) = aA;
        }
        __syncthreads();                                               // B8
        if (tid < 256) {
            float v = ns_b1[c];
            #pragma unroll
            for (int i = 0; i < 8; ++i) v += s_part[(i << 8) + c];
            v = fast_tanh(v);
            const unsigned int pk = packpair(v);
            if (!(lane & 1)) s_a_h[c >> 1] = pk;
        }
        __syncthreads();                                               // B9

        // ---- ns2 (K=256, src s_a_h) + state update ----
        {
            float4 aA = make_float4(0, 0, 0, 0);
            const int kp0 = w << 4;
            #pragma unroll 4
            for (int i = 0; i < 16; ++i) {
                const int kp = kp0 + i;
                const unsigned int x = s_a_h[kp];
                const uint4 wa = *(const uint4*)(NS2 + (size_t)kp * 256 + cl4);
                aA.x = dot2f(wa.x, x, aA.x); aA.y = dot2f(wa.y, x, aA.y);
                aA.z = dot2f(wa.z, x, aA.z); aA.w = dot2f(wa.w, x, aA.w);
            }
            *(float4*)(s_part + (w << 8) + cl4) = aA;
        }
        __syncthreads();                                               // B10
        if (tid < 256) {
            float nsv = ns_b2[c];
            #pragma unroll
            for (int i = 0; i < 8; ++i) nsv += s_part[(i << 8) + c];
            const float u = r_u, ut = s_ut[c];
            const float ny  = (1.f - u)  * nsv + u  * r_ydec;
            const float nyt = (1.f - ut) * nsv + ut * r_yt;
            r_y  = maskv ? ny  : r_ydec;
            r_yt = maskv ? nyt : r_yt;
            const unsigned int pk = packpair(r_y);
            if (!(lane & 1)) s_y_h[c >> 1] = pk;
        }
        __syncthreads();                                               // B11
    }

    if (tid < 256)
        out[(size_t)traj * 256 + c] = r_y;
}

extern "C" void kernel_launch(void* const* d_in, const int* in_sizes, int n_in,
                              void* d_out, int out_size, void* d_ws, size_t ws_size,
                              hipStream_t stream) {
    const float* data   = (const float*)d_in[0];
    const float* ts     = (const float*)d_in[1];
    const float* ug_w1  = (const float*)d_in[2];
    const float* ug_b1  = (const float*)d_in[3];
    const float* ug_w2  = (const float*)d_in[4];
    const float* ug_b2  = (const float*)d_in[5];
    const float* ugt_w1 = (const float*)d_in[6];
    const float* ugt_b1 = (const float*)d_in[7];
    const float* ugt_w2 = (const float*)d_in[8];
    const float* ugt_b2 = (const float*)d_in[9];
    const float* rg_w1  = (const float*)d_in[10];
    const float* rg_b1  = (const float*)d_in[11];
    const float* rg_w2  = (const float*)d_in[12];
    const float* rg_b2  = (const float*)d_in[13];
    // d_in[14..17] = rgt_* : unused by the reference
    const float* ns_w1  = (const float*)d_in[18];
    const float* ns_b1  = (const float*)d_in[19];
    const float* ns_w2  = (const float*)d_in[20];
    const float* ns_b2  = (const float*)d_in[21];
    const float* dk_w1  = (const float*)d_in[22];
    const float* dk_b1  = (const float*)d_in[23];
    const float* dk_w2  = (const float*)d_in[24];
    const float* dk_b2  = (const float*)d_in[25];
    const float* dec_w  = (const float*)d_in[26];
    const float* dec_b  = (const float*)d_in[27];

    unsigned int* wsu = (unsigned int*)d_ws;

    convert_w<<<WU_TOT / 256, 256, 0, stream>>>(ug_w1, ug_w2, ugt_w1, ugt_w2,
                                                rg_w1, rg_w2, ns_w1, ns_w2,
                                                dk_w1, dec_w, wsu);

    rnn_decay_kernel3<<<NTRAJ, 512, 0, stream>>>(
        data, ts, ug_b1, ug_b2, ugt_b1, ugt_b2, rg_b1, rg_b2, ns_b1, ns_b2,
        dk_b1, dk_w2, dk_b2, dec_b, wsu, (float*)d_out);
}